// Round 1
// baseline (2675.904 us; speedup 1.0000x reference)
//
#include <hip/hip_runtime.h>
#include <cstdint>

#define DEV __device__ __forceinline__

typedef __bf16 bf16x8 __attribute__((ext_vector_type(8)));
typedef float f32x4 __attribute__((ext_vector_type(4)));

// ---------- bf16 helpers (RNE) ----------
DEV uint16_t f2b(float f) {
  uint32_t u = __builtin_bit_cast(uint32_t, f);
  u = u + 0x7fffu + ((u >> 16) & 1u);
  return (uint16_t)(u >> 16);
}
DEV float b2f(uint16_t h) { return __builtin_bit_cast(float, (uint32_t)h << 16); }
DEV float b2f_lo(uint32_t u) { return __builtin_bit_cast(float, u << 16); }
DEV float b2f_hi(uint32_t u) { return __builtin_bit_cast(float, u & 0xffff0000u); }

// ---------- async global->LDS (16B per lane) ----------
DEV void gload16(const void* g, void* s) {
  __builtin_amdgcn_global_load_lds((const __attribute__((address_space(1))) uint32_t*)g,
                                   (__attribute__((address_space(3))) uint32_t*)s, 16, 0, 0);
}

DEV float wave_max(float v) {
#pragma unroll
  for (int off = 32; off; off >>= 1) v = fmaxf(v, __shfl_xor(v, off));
  return v;
}
DEV float wave_sum(float v) {
#pragma unroll
  for (int off = 32; off; off >>= 1) v += __shfl_xor(v, off);
  return v;
}

// ---------- prep kernels ----------
__global__ void k_convert_bf16(const float* __restrict__ X, uint16_t* __restrict__ Xb, int n4) {
  int i = blockIdx.x * 256 + threadIdx.x;
  if (i >= n4) return;
  float4 v = ((const float4*)X)[i];
  uint16_t o0 = f2b(v.x), o1 = f2b(v.y), o2 = f2b(v.z), o3 = f2b(v.w);
  uint64_t packed = (uint64_t)o0 | ((uint64_t)o1 << 16) | ((uint64_t)o2 << 32) | ((uint64_t)o3 << 48);
  ((uint64_t*)Xb)[i] = packed;
}

// W[R][C] f32 -> Wt[C][R] bf16  (coalesced writes)
__global__ void k_transpose_bf16(const float* __restrict__ W, uint16_t* __restrict__ Wt, int R, int C) {
  int idx = blockIdx.x * 256 + threadIdx.x;
  if (idx >= R * C) return;
  int c = idx / R, r = idx - c * R;
  Wt[(size_t)c * R + r] = f2b(W[(size_t)r * C + c]);
}

__global__ void k_rope(float* __restrict__ rc, float* __restrict__ rs) {
  int idx = blockIdx.x * 256 + threadIdx.x;  // T*32
  if (idx >= 2048 * 32) return;
  int t = idx >> 5, j = idx & 31;
  float inv = powf(10000.f, -(float)j / 32.f);
  float ang = (float)t * inv;
  rc[idx] = cosf(ang);
  rs[idx] = sinf(ang);
}

// ---------- bf16 MFMA GEMM, C = A * Bt^T ----------
// A: [M][K] bf16 row-major; Bt: [N][K] bf16 row-major.
// MODE 0: epilogue = RoPE + split-store Q/K/V bf16 [B=4][H=16][T=2048][64]
// MODE 1: epilogue = +bias, f32 store to Cout [M][N]
template <int MODE>
__global__ __launch_bounds__(256) void gemm_bt(
    const uint16_t* __restrict__ A, const uint16_t* __restrict__ Bt,
    int M, int N, int K,
    uint16_t* __restrict__ Qd, uint16_t* __restrict__ Kd, uint16_t* __restrict__ Vd,
    const float* __restrict__ rc, const float* __restrict__ rs,
    float* __restrict__ Cout, const float* __restrict__ bias) {
  __shared__ uint16_t sA[128 * 32];
  __shared__ uint16_t sB[128 * 32];
  const int tid = threadIdx.x;
  const int w = tid >> 6, lane = tid & 63;
  const int wr = w >> 1, wc = w & 1;
  const int bm = blockIdx.y * 128, bn = blockIdx.x * 128;

  f32x4 acc[4][4] = {};

  const int sRow = lane >> 2;        // row within 16-row chunk
  const int sK = (lane & 3) * 8;     // k offset (elems)

  for (int kt = 0; kt < K; kt += 32) {
#pragma unroll
    for (int i = 0; i < 2; ++i) {
      const int ci = w * 2 + i;  // chunk 0..7 (16 rows each)
      gload16(A + (size_t)(bm + ci * 16 + sRow) * K + kt + sK, &sA[ci * 512]);
      gload16(Bt + (size_t)(bn + ci * 16 + sRow) * K + kt + sK, &sB[ci * 512]);
    }
    __syncthreads();
    bf16x8 af[4], bfr[4];
#pragma unroll
    for (int mi = 0; mi < 4; ++mi)
      af[mi] = *(const bf16x8*)&sA[(wr * 64 + mi * 16 + (lane & 15)) * 32 + (lane >> 4) * 8];
#pragma unroll
    for (int ni = 0; ni < 4; ++ni)
      bfr[ni] = *(const bf16x8*)&sB[(wc * 64 + ni * 16 + (lane & 15)) * 32 + (lane >> 4) * 8];
#pragma unroll
    for (int mi = 0; mi < 4; ++mi)
#pragma unroll
      for (int ni = 0; ni < 4; ++ni)
        acc[mi][ni] = __builtin_amdgcn_mfma_f32_16x16x32_bf16(af[mi], bfr[ni], acc[mi][ni], 0, 0, 0);
    __syncthreads();
  }

  const int lr = lane >> 4, lc = lane & 15;
#pragma unroll
  for (int mi = 0; mi < 4; ++mi) {
#pragma unroll
    for (int ni = 0; ni < 4; ++ni) {
      const int colb = bn + wc * 64 + ni * 16 + lc;
#pragma unroll
      for (int r = 0; r < 4; ++r) {
        const int row = bm + wr * 64 + mi * 16 + lr * 4 + r;
        float val = acc[mi][ni][r];
        if (MODE == 0) {
          const int b = row >> 11, t = row & 2047;
          const float pv = __shfl_xor(val, 1);  // partner column (d^1), lane-adjacent
          if (colb < 2048) {
            const int d = colb & 63, j = d >> 1;
            const float c = rc[t * 32 + j], s = rs[t * 32 + j];
            const float rv = (d & 1) ? (val * c + pv * s) : (val * c - pv * s);
            const int cc = colb & 1023, h = cc >> 6;
            uint16_t* dst = (colb < 1024) ? Qd : Kd;
            dst[((((size_t)b * 16 + h) * 2048 + t) << 6) + d] = f2b(rv);
          } else {
            const int cc = colb - 2048;
            const int h = cc >> 6, d = cc & 63;
            Vd[((((size_t)b * 16 + h) * 2048 + t) << 6) + d] = f2b(val);
          }
        } else {
          Cout[(size_t)row * N + colb] = val + bias[colb];
        }
      }
    }
  }
}

// ---------- block-sparse causal attention (scalar/wave-parallel, f32 accum) ----------
// Q/K/V: bf16 [BH=64][T=2048][64]. O: bf16 [B*T][1024] (head-major cols).
// allowed(k,t): k<=t && (t-k<=127 || k%64==0 || t%64==0)
__global__ __launch_bounds__(256) void attn_sparse(const uint16_t* __restrict__ Qd,
                                                   const uint16_t* __restrict__ Kd,
                                                   const uint16_t* __restrict__ Vd,
                                                   uint16_t* __restrict__ O) {
  __shared__ float qsh[4][64];
  const int tid = threadIdx.x;
  const int wv = tid >> 6, lane = tid & 63;
  const int bh = blockIdx.x >> 9;                 // 512 blocks per (b,h)
  const int t = ((blockIdx.x & 511) << 2) + wv;   // 4 rows per block (one per wave)
  const size_t hb = (size_t)bh * (2048 * 64);

  qsh[wv][lane] = b2f(Qd[hb + (size_t)t * 64 + lane]);
  __syncthreads();
  const float* qp = qsh[wv];

  float m = -1e30f, lsum = 0.f, acc = 0.f;

  auto batch = [&](int kb, int mode, int ng) {  // mode 0=local(masked), 1=full-causal, 2=globals
    int key;
    bool ok;
    if (mode == 2) {
      key = lane << 6;
      ok = lane < ng;
    } else {
      key = kb + lane;
      ok = key <= t;
      if (mode == 0) ok = ok && (key >= t - 127 || (key & 63) == 0);
    }
    float sc = -1e30f;
    if (ok) {
      const uint16_t* kr = Kd + hb + (size_t)key * 64;
      float s = 0.f;
#pragma unroll
      for (int i = 0; i < 8; ++i) {
        uint4 kvv = *(const uint4*)(kr + i * 8);
        float4 qa = *(const float4*)(qp + i * 8);
        float4 qb = *(const float4*)(qp + i * 8 + 4);
        s += qa.x * b2f_lo(kvv.x) + qa.y * b2f_hi(kvv.x)
           + qa.z * b2f_lo(kvv.y) + qa.w * b2f_hi(kvv.y)
           + qb.x * b2f_lo(kvv.z) + qb.y * b2f_hi(kvv.z)
           + qb.z * b2f_lo(kvv.w) + qb.w * b2f_hi(kvv.w);
      }
      sc = s * 0.125f;
    }
    float bm = wave_max(sc);
    if (bm > -1e29f) {
      float mn = fmaxf(m, bm);
      float corr = __expf(m - mn);
      float p = ok ? __expf(sc - mn) : 0.f;
      float ps = wave_sum(p);
      lsum = lsum * corr + ps;
      acc *= corr;
      m = mn;
      int cnt;
      if (mode == 2) cnt = ng;
      else { cnt = t - kb + 1; if (cnt > 64) cnt = 64; }
      for (int kk = 0; kk < cnt; ++kk) {
        float pk = __shfl(p, kk);
        int k2 = (mode == 2) ? (kk << 6) : (kb + kk);
        acc += pk * b2f(Vd[hb + (size_t)k2 * 64 + lane]);  // coalesced 128B row
      }
    }
  };

  if ((t & 63) == 0) {
    for (int kb = 0; kb <= t; kb += 64) batch(kb, 1, 0);
  } else {
    int lo = t - 127; if (lo < 0) lo = 0;
    int kbs = lo & ~63;
    for (int kb = kbs; kb <= t; kb += 64) batch(kb, 0, 0);
    int ng = kbs >> 6;
    if (ng > 0) batch(0, 2, ng);
  }

  const int b = bh >> 4, h = bh & 15;
  O[((size_t)(b * 2048 + t) * 1024) + h * 64 + lane] = f2b(acc / lsum);
}

// ---------- launch ----------
extern "C" void kernel_launch(void* const* d_in, const int* in_sizes, int n_in,
                              void* d_out, int out_size, void* d_ws, size_t ws_size,
                              hipStream_t stream) {
  const float* x = (const float*)d_in[0];
  const float* W_qkv = (const float*)d_in[1];
  const float* W_out = (const float*)d_in[2];
  const float* b_out = (const float*)d_in[3];

  char* ws = (char*)d_ws;
  size_t off = 0;
  auto alloc = [&](size_t bytes) {
    void* p = ws + off;
    off += (bytes + 255) & ~(size_t)255;
    return p;
  };
  uint16_t* xb = (uint16_t*)alloc(8192ull * 1024 * 2);    // x bf16 (reused as attn-out)
  uint16_t* wqkvt = (uint16_t*)alloc(3072ull * 1024 * 2); // W_qkv^T bf16
  uint16_t* woutt = (uint16_t*)alloc(1024ull * 1024 * 2); // W_out^T bf16
  float* rc = (float*)alloc(2048ull * 32 * 4);
  float* rs = (float*)alloc(2048ull * 32 * 4);
  uint16_t* Qd = (uint16_t*)alloc(8192ull * 1024 * 2);
  uint16_t* Kd = (uint16_t*)alloc(8192ull * 1024 * 2);
  uint16_t* Vd = (uint16_t*)alloc(8192ull * 1024 * 2);
  uint16_t* O = xb;  // alias: xb dead after GEMM1

  k_convert_bf16<<<8192, 256, 0, stream>>>(x, xb, 8192 * 1024 / 4);
  k_transpose_bf16<<<(1024 * 3072 + 255) / 256, 256, 0, stream>>>(W_qkv, wqkvt, 1024, 3072);
  k_transpose_bf16<<<(1024 * 1024 + 255) / 256, 256, 0, stream>>>(W_out, woutt, 1024, 1024);
  k_rope<<<2048 * 32 / 256, 256, 0, stream>>>(rc, rs);

  gemm_bt<0><<<dim3(24, 64), 256, 0, stream>>>(xb, wqkvt, 8192, 3072, 1024,
                                               Qd, Kd, Vd, rc, rs, nullptr, nullptr);
  attn_sparse<<<32768, 256, 0, stream>>>(Qd, Kd, Vd, O);
  gemm_bt<1><<<dim3(8, 64), 256, 0, stream>>>(O, woutt, 8192, 1024, 1024,
                                              nullptr, nullptr, nullptr, nullptr, nullptr,
                                              (float*)d_out, b_out);
}

// Round 2
// 222.512 us; speedup vs baseline: 12.0259x; 12.0259x over previous
//
#include <hip/hip_runtime.h>
#include <cstdint>

#define DEV __device__ __forceinline__

typedef __bf16 bf16x8 __attribute__((ext_vector_type(8)));
typedef float f32x4 __attribute__((ext_vector_type(4)));
typedef float f32x16 __attribute__((ext_vector_type(16)));
typedef uint32_t u32x4 __attribute__((ext_vector_type(4)));

// ---------- bf16 helpers (RNE) ----------
DEV uint16_t f2b(float f) {
  uint32_t u = __builtin_bit_cast(uint32_t, f);
  u = u + 0x7fffu + ((u >> 16) & 1u);
  return (uint16_t)(u >> 16);
}
DEV uint32_t pk2(float lo, float hi) {
  return (uint32_t)f2b(lo) | ((uint32_t)f2b(hi) << 16);
}

DEV f32x16 mfma32(bf16x8 a, bf16x8 b, f32x16 c) {
  return __builtin_amdgcn_mfma_f32_32x32x16_bf16(a, b, c, 0, 0, 0);
}

// ---------- async global->LDS (16B per lane) ----------
DEV void gload16(const void* g, void* s) {
  __builtin_amdgcn_global_load_lds((const __attribute__((address_space(1))) uint32_t*)g,
                                   (__attribute__((address_space(3))) uint32_t*)s, 16, 0, 0);
}

// ---------- prep kernels ----------
__global__ void k_convert_bf16(const float* __restrict__ X, uint16_t* __restrict__ Xb, int n4) {
  int i = blockIdx.x * 256 + threadIdx.x;
  if (i >= n4) return;
  float4 v = ((const float4*)X)[i];
  uint16_t o0 = f2b(v.x), o1 = f2b(v.y), o2 = f2b(v.z), o3 = f2b(v.w);
  uint64_t packed = (uint64_t)o0 | ((uint64_t)o1 << 16) | ((uint64_t)o2 << 32) | ((uint64_t)o3 << 48);
  ((uint64_t*)Xb)[i] = packed;
}

__global__ void k_transpose_bf16(const float* __restrict__ W, uint16_t* __restrict__ Wt, int R, int C) {
  int idx = blockIdx.x * 256 + threadIdx.x;
  if (idx >= R * C) return;
  int c = idx / R, r = idx - c * R;
  Wt[(size_t)c * R + r] = f2b(W[(size_t)r * C + c]);
}

__global__ void k_rope(float* __restrict__ rc, float* __restrict__ rs) {
  int idx = blockIdx.x * 256 + threadIdx.x;  // T*32
  if (idx >= 2048 * 32) return;
  int t = idx >> 5, j = idx & 31;
  float inv = powf(10000.f, -(float)j / 32.f);
  float ang = (float)t * inv;
  rc[idx] = cosf(ang);
  rs[idx] = sinf(ang);
}

// V[bh][2048][64] -> Vt[bh][64][2048]
__global__ __launch_bounds__(256) void k_transpose_v(const uint16_t* __restrict__ V,
                                                     uint16_t* __restrict__ Vt) {
  __shared__ uint16_t sh[64][72];
  const int tid = threadIdx.x;
  const int bh = blockIdx.x >> 5;
  const int t0 = (blockIdx.x & 31) * 64;
#pragma unroll
  for (int it = 0; it < 2; ++it) {
    const int idx = it * 256 + tid;
    const int tr = idx >> 3, d8 = (idx & 7) * 8;
    uint4 vv = *(const uint4*)&V[((size_t)(bh << 11) + t0 + tr) * 64 + d8];
    const uint16_t* e = (const uint16_t*)&vv;
#pragma unroll
    for (int j = 0; j < 8; ++j) sh[d8 + j][tr] = e[j];
  }
  __syncthreads();
#pragma unroll
  for (int it = 0; it < 2; ++it) {
    const int idx = it * 256 + tid;
    const int d = idx >> 3, t8 = (idx & 7) * 8;
    uint16_t tmp[8];
#pragma unroll
    for (int j = 0; j < 8; ++j) tmp[j] = sh[d][t8 + j];
    *(uint4*)&Vt[((size_t)bh * 64 + d) * 2048 + t0 + t8] = *(uint4*)tmp;
  }
}

// Gather global-key/query tiles: Kg/Qg[bh][32][64], Vtg[bh][64][32]
__global__ __launch_bounds__(256) void k_gather(const uint16_t* __restrict__ Qd,
                                                const uint16_t* __restrict__ Kd,
                                                const uint16_t* __restrict__ Vt,
                                                uint16_t* __restrict__ Qg,
                                                uint16_t* __restrict__ Kg,
                                                uint16_t* __restrict__ Vtg) {
  const int tid = threadIdx.x;
  const int bh = blockIdx.x;
  {
    const int g = tid >> 3, d8 = (tid & 7) * 8;
    const size_t src = ((size_t)(bh << 11) + g * 64) * 64 + d8;
    const size_t dst = ((size_t)bh * 32 + g) * 64 + d8;
    *(uint4*)&Kg[dst] = *(const uint4*)&Kd[src];
    *(uint4*)&Qg[dst] = *(const uint4*)&Qd[src];
  }
  {
    const int d = tid >> 2, g8 = (tid & 3) * 8;
    uint16_t tmp[8];
#pragma unroll
    for (int j = 0; j < 8; ++j) tmp[j] = Vt[((size_t)bh * 64 + d) * 2048 + (size_t)(g8 + j) * 64];
    *(uint4*)&Vtg[((size_t)bh * 64 + d) * 32 + g8] = *(uint4*)tmp;
  }
}

// ---------- bf16 MFMA GEMM, C = A * Bt^T (16x16x32, 128^2 tile) ----------
template <int MODE>
__global__ __launch_bounds__(256) void gemm_bt(
    const uint16_t* __restrict__ A, const uint16_t* __restrict__ Bt,
    int M, int N, int K,
    uint16_t* __restrict__ Qd, uint16_t* __restrict__ Kd, uint16_t* __restrict__ Vd,
    const float* __restrict__ rc, const float* __restrict__ rs,
    float* __restrict__ Cout, const float* __restrict__ bias) {
  __shared__ uint16_t sA[128 * 32];
  __shared__ uint16_t sB[128 * 32];
  const int tid = threadIdx.x;
  const int w = tid >> 6, lane = tid & 63;
  const int wr = w >> 1, wc = w & 1;
  const int bm = blockIdx.y * 128, bn = blockIdx.x * 128;

  f32x4 acc[4][4] = {};

  const int sRow = lane >> 2;
  const int sK = (lane & 3) * 8;

  for (int kt = 0; kt < K; kt += 32) {
#pragma unroll
    for (int i = 0; i < 2; ++i) {
      const int ci = w * 2 + i;
      gload16(A + (size_t)(bm + ci * 16 + sRow) * K + kt + sK, &sA[ci * 512]);
      gload16(Bt + (size_t)(bn + ci * 16 + sRow) * K + kt + sK, &sB[ci * 512]);
    }
    __syncthreads();
    bf16x8 af[4], bfr[4];
#pragma unroll
    for (int mi = 0; mi < 4; ++mi)
      af[mi] = *(const bf16x8*)&sA[(wr * 64 + mi * 16 + (lane & 15)) * 32 + (lane >> 4) * 8];
#pragma unroll
    for (int ni = 0; ni < 4; ++ni)
      bfr[ni] = *(const bf16x8*)&sB[(wc * 64 + ni * 16 + (lane & 15)) * 32 + (lane >> 4) * 8];
#pragma unroll
    for (int mi = 0; mi < 4; ++mi)
#pragma unroll
      for (int ni = 0; ni < 4; ++ni)
        acc[mi][ni] = __builtin_amdgcn_mfma_f32_16x16x32_bf16(af[mi], bfr[ni], acc[mi][ni], 0, 0, 0);
    __syncthreads();
  }

  const int lr = lane >> 4, lc = lane & 15;
#pragma unroll
  for (int mi = 0; mi < 4; ++mi) {
#pragma unroll
    for (int ni = 0; ni < 4; ++ni) {
      const int colb = bn + wc * 64 + ni * 16 + lc;
#pragma unroll
      for (int r = 0; r < 4; ++r) {
        const int row = bm + wr * 64 + mi * 16 + lr * 4 + r;
        float val = acc[mi][ni][r];
        if (MODE == 0) {
          const int b = row >> 11, t = row & 2047;
          const float pv = __shfl_xor(val, 1);
          if (colb < 2048) {
            const int d = colb & 63, j = d >> 1;
            const float c = rc[t * 32 + j], s = rs[t * 32 + j];
            const float rv = (d & 1) ? (val * c + pv * s) : (val * c - pv * s);
            const int cc = colb & 1023, h = cc >> 6;
            uint16_t* dst = (colb < 1024) ? Qd : Kd;
            dst[((((size_t)b * 16 + h) * 2048 + t) << 6) + d] = f2b(rv);
          } else {
            const int cc = colb - 2048;
            const int h = cc >> 6, d = cc & 63;
            Vd[((((size_t)b * 16 + h) * 2048 + t) << 6) + d] = f2b(val);
          }
        } else {
          Cout[(size_t)row * N + colb] = val + bias[colb];
        }
      }
    }
  }
}

// ---------- MFMA flash-attention tile step (32x32x16, swapped QK^T) ----------
// MASK 0: local  (key=kb+crow; ok = key<=qv && key+127>=qv)
// MASK 1: gathered globals (ok = 64*crow <= qv-128)
// MASK 2: full causal, gathered queries (key=kb+crow; ok = key<=qv)
template <int MASK>
DEV void attn_tile(const uint16_t* __restrict__ kb_ptr, const uint16_t* __restrict__ v_ptr,
                   const int vrs, const int kb, const int qv, const int hi, const int ln,
                   const bf16x8 qf[4], float& m, float& l, f32x16& acc0, f32x16& acc1) {
  bf16x8 kf0 = *(const bf16x8*)&kb_ptr[ln * 64 + 0 + hi * 8];
  bf16x8 kf1 = *(const bf16x8*)&kb_ptr[ln * 64 + 16 + hi * 8];
  bf16x8 kf2 = *(const bf16x8*)&kb_ptr[ln * 64 + 32 + hi * 8];
  bf16x8 kf3 = *(const bf16x8*)&kb_ptr[ln * 64 + 48 + hi * 8];
  bf16x8 vf00 = *(const bf16x8*)&v_ptr[ln * vrs + hi * 8];
  bf16x8 vf01 = *(const bf16x8*)&v_ptr[ln * vrs + 16 + hi * 8];
  bf16x8 vf10 = *(const bf16x8*)&v_ptr[(32 + ln) * vrs + hi * 8];
  bf16x8 vf11 = *(const bf16x8*)&v_ptr[(32 + ln) * vrs + 16 + hi * 8];

  f32x16 sv = {};
  sv = mfma32(kf0, qf[0], sv);
  sv = mfma32(kf1, qf[1], sv);
  sv = mfma32(kf2, qf[2], sv);
  sv = mfma32(kf3, qf[3], sv);

  float s[16];
  float pm = -3.0e38f;
#pragma unroll
  for (int r = 0; r < 16; ++r) {
    const int crow = (r & 3) + 8 * (r >> 2) + 4 * hi;
    bool ok;
    if (MASK == 0) {
      const int key = kb + crow;
      ok = (key <= qv) && (key + 127 >= qv);
    } else if (MASK == 1) {
      ok = crow * 64 <= qv - 128;
    } else {
      const int key = kb + crow;
      ok = (key <= qv);
    }
    s[r] = ok ? sv[r] * 0.125f : -3.0e38f;
    pm = fmaxf(pm, s[r]);
  }
  pm = fmaxf(pm, __shfl_xor(pm, 32));

  if (__any(pm > m + 8.0f)) {  // rescale (rare after first tile: defer-max T13)
    const float mn = fmaxf(m, pm);
    const float f = __expf(m - mn);
#pragma unroll
    for (int r = 0; r < 16; ++r) {
      const int crow = (r & 3) + 8 * (r >> 2) + 4 * hi;
      const float fr = __shfl(f, crow);
      acc0[r] *= fr;
      acc1[r] *= fr;
    }
    l *= f;
    m = mn;
  }

  float p[16];
  float ps = 0.f;
#pragma unroll
  for (int r = 0; r < 16; ++r) {
    p[r] = __expf(s[r] - m);
    ps += p[r];
  }
  l += ps + __shfl_xor(ps, 32);

  // pack P rows (runs of 4 consecutive keys) and exchange halves (lane^32)
  const uint32_t q0a = pk2(p[0], p[1]), q0b = pk2(p[2], p[3]);
  const uint32_t q1a = pk2(p[4], p[5]), q1b = pk2(p[6], p[7]);
  const uint32_t q2a = pk2(p[8], p[9]), q2b = pk2(p[10], p[11]);
  const uint32_t q3a = pk2(p[12], p[13]), q3b = pk2(p[14], p[15]);
  const uint32_t p0a = __shfl_xor(q0a, 32), p0b = __shfl_xor(q0b, 32);
  const uint32_t p1a = __shfl_xor(q1a, 32), p1b = __shfl_xor(q1b, 32);
  const uint32_t p2a = __shfl_xor(q2a, 32), p2b = __shfl_xor(q2b, 32);
  const uint32_t p3a = __shfl_xor(q3a, 32), p3b = __shfl_xor(q3b, 32);
  u32x4 f0, f1;
  f0[0] = hi ? p1a : q0a; f0[1] = hi ? p1b : q0b; f0[2] = hi ? q1a : p0a; f0[3] = hi ? q1b : p0b;
  f1[0] = hi ? p3a : q2a; f1[1] = hi ? p3b : q2b; f1[2] = hi ? q3a : p2a; f1[3] = hi ? q3b : p2b;
  const bf16x8 pa0 = __builtin_bit_cast(bf16x8, f0);
  const bf16x8 pa1 = __builtin_bit_cast(bf16x8, f1);

  acc0 = mfma32(pa0, vf00, acc0);
  acc0 = mfma32(pa1, vf01, acc0);
  acc1 = mfma32(pa0, vf10, acc1);
  acc1 = mfma32(pa1, vf11, acc1);
}

// Main sparse attention: 1 wave = 32 queries; <=5 local K-tiles + 1 gathered-global tile.
__global__ __launch_bounds__(256) void attn_main(const uint16_t* __restrict__ Qd,
                                                 const uint16_t* __restrict__ Kd,
                                                 const uint16_t* __restrict__ Vt,
                                                 const uint16_t* __restrict__ Kg,
                                                 const uint16_t* __restrict__ Vtg,
                                                 uint16_t* __restrict__ O) {
  const int tid = threadIdx.x;
  const int wid = blockIdx.x * 4 + (tid >> 6);
  const int bh = wid >> 6, qt = wid & 63;
  const int qb = qt * 32;
  const int lane = tid & 63, hi = lane >> 5, ln = lane & 31;
  const int qv = qb + ln;

  bf16x8 qf[4];
#pragma unroll
  for (int i = 0; i < 4; ++i)
    qf[i] = *(const bf16x8*)&Qd[((size_t)(bh << 11) + qv) * 64 + i * 16 + hi * 8];

  float m = -1e30f, l = 0.f;
  f32x16 acc0 = {}, acc1 = {};

  const int kb0 = qb >= 128 ? qb - 128 : 0;
  for (int kbb = kb0; kbb <= qb; kbb += 32)
    attn_tile<0>(Kd + ((size_t)(bh << 11) + kbb) * 64, Vt + (size_t)bh * 64 * 2048 + kbb, 2048,
                 kbb, qv, hi, ln, qf, m, l, acc0, acc1);
  if (qb >= 128)
    attn_tile<1>(Kg + (size_t)bh * 32 * 64, Vtg + (size_t)bh * 64 * 32, 32,
                 0, qv, hi, ln, qf, m, l, acc0, acc1);

  const float linv = 1.0f / l;
  const int b = bh >> 4, h = bh & 15;
  const int ocol = h * 64 + ln;
#pragma unroll
  for (int r = 0; r < 16; ++r) {
    const int crow = (r & 3) + 8 * (r >> 2) + 4 * hi;
    const float sc = __shfl(linv, crow);
    const size_t orow = (size_t)(b * 2048 + qb + crow);
    O[orow * 1024 + ocol] = f2b(acc0[r] * sc);
    O[orow * 1024 + ocol + 32] = f2b(acc1[r] * sc);
  }
}

// Global-query rows (t%64==0): full causal, 1 block per (b,h), 4 waves split K, LDS merge.
__global__ __launch_bounds__(256) void attn_global(const uint16_t* __restrict__ Qg,
                                                   const uint16_t* __restrict__ Kd,
                                                   const uint16_t* __restrict__ Vt,
                                                   uint16_t* __restrict__ O) {
  __shared__ float accL[4][32][64];
  __shared__ float mL[4][32];
  __shared__ float lL[4][32];
  const int tid = threadIdx.x;
  const int bh = blockIdx.x;
  const int wv = tid >> 6, lane = tid & 63, hi = lane >> 5, ln = lane & 31;
  const int qv = ln * 64;  // actual query position

  bf16x8 qf[4];
#pragma unroll
  for (int i = 0; i < 4; ++i)
    qf[i] = *(const bf16x8*)&Qg[((size_t)bh * 32 + ln) * 64 + i * 16 + hi * 8];

  float m = -1e30f, l = 0.f;
  f32x16 acc0 = {}, acc1 = {};
  for (int kt = wv; kt < 64; kt += 4) {
    const int kbb = kt * 32;
    attn_tile<2>(Kd + ((size_t)(bh << 11) + kbb) * 64, Vt + (size_t)bh * 64 * 2048 + kbb, 2048,
                 kbb, qv, hi, ln, qf, m, l, acc0, acc1);
  }

  if (hi == 0) {
    mL[wv][ln] = m;
    lL[wv][ln] = l;
  }
#pragma unroll
  for (int r = 0; r < 16; ++r) {
    const int crow = (r & 3) + 8 * (r >> 2) + 4 * hi;
    accL[wv][crow][ln] = acc0[r];
    accL[wv][crow][ln + 32] = acc1[r];
  }
  __syncthreads();

  const int q = tid >> 3, d0 = (tid & 7) * 8;
  float M = fmaxf(fmaxf(mL[0][q], mL[1][q]), fmaxf(mL[2][q], mL[3][q]));
  float L = 0.f;
  float v[8] = {};
#pragma unroll
  for (int w = 0; w < 4; ++w) {
    const float ew = __expf(mL[w][q] - M);
    L += lL[w][q] * ew;
#pragma unroll
    for (int j = 0; j < 8; ++j) v[j] += accL[w][q][d0 + j] * ew;
  }
  const float Li = 1.0f / L;
  const int b = bh >> 4, h = bh & 15;
  const size_t orow = (size_t)(b * 2048 + q * 64);
#pragma unroll
  for (int j = 0; j < 8; ++j) O[orow * 1024 + h * 64 + d0 + j] = f2b(v[j] * Li);
}

// ---------- launch ----------
extern "C" void kernel_launch(void* const* d_in, const int* in_sizes, int n_in,
                              void* d_out, int out_size, void* d_ws, size_t ws_size,
                              hipStream_t stream) {
  const float* x = (const float*)d_in[0];
  const float* W_qkv = (const float*)d_in[1];
  const float* W_out = (const float*)d_in[2];
  const float* b_out = (const float*)d_in[3];

  char* ws = (char*)d_ws;
  size_t off = 0;
  auto alloc = [&](size_t bytes) {
    void* p = ws + off;
    off += (bytes + 255) & ~(size_t)255;
    return p;
  };
  uint16_t* xb = (uint16_t*)alloc(8192ull * 1024 * 2);     // x bf16 (reused as attn-out O)
  uint16_t* wqkvt = (uint16_t*)alloc(3072ull * 1024 * 2);  // W_qkv^T bf16
  uint16_t* woutt = (uint16_t*)alloc(1024ull * 1024 * 2);  // W_out^T bf16
  float* rc = (float*)alloc(2048ull * 32 * 4);
  float* rs = (float*)alloc(2048ull * 32 * 4);
  uint16_t* Qd = (uint16_t*)alloc(8192ull * 1024 * 2);
  uint16_t* Kd = (uint16_t*)alloc(8192ull * 1024 * 2);
  uint16_t* Vd = (uint16_t*)alloc(8192ull * 1024 * 2);
  uint16_t* Vt = (uint16_t*)alloc(8192ull * 1024 * 2);     // V transposed [bh][64][2048]
  uint16_t* Qg = (uint16_t*)alloc(64ull * 32 * 64 * 2);
  uint16_t* Kg = (uint16_t*)alloc(64ull * 32 * 64 * 2);
  uint16_t* Vtg = (uint16_t*)alloc(64ull * 64 * 32 * 2);
  uint16_t* O = xb;  // alias: xb dead after GEMM1

  k_convert_bf16<<<8192, 256, 0, stream>>>(x, xb, 8192 * 1024 / 4);
  k_transpose_bf16<<<(1024 * 3072 + 255) / 256, 256, 0, stream>>>(W_qkv, wqkvt, 1024, 3072);
  k_transpose_bf16<<<(1024 * 1024 + 255) / 256, 256, 0, stream>>>(W_out, woutt, 1024, 1024);
  k_rope<<<2048 * 32 / 256, 256, 0, stream>>>(rc, rs);

  gemm_bt<0><<<dim3(24, 64), 256, 0, stream>>>(xb, wqkvt, 8192, 3072, 1024,
                                               Qd, Kd, Vd, rc, rs, nullptr, nullptr);

  k_transpose_v<<<2048, 256, 0, stream>>>(Vd, Vt);
  k_gather<<<64, 256, 0, stream>>>(Qd, Kd, Vt, Qg, Kg, Vtg);

  attn_main<<<1024, 256, 0, stream>>>(Qd, Kd, Vt, Kg, Vtg, O);
  attn_global<<<64, 256, 0, stream>>>(Qg, Kd, Vt, O);

  gemm_bt<1><<<dim3(8, 64), 256, 0, stream>>>(O, woutt, 8192, 1024, 1024,
                                              nullptr, nullptr, nullptr, nullptr, nullptr,
                                              (float*)d_out, b_out);
}